// Round 4
// baseline (6085.612 us; speedup 1.0000x reference)
//
#include <hip/hip_runtime.h>
#include <math.h>

#define BB 2
#define LL 2048
#define DM 1024
#define NH 16
#define HD 64

__device__ __forceinline__ unsigned mono32(float f) {
    unsigned u = __float_as_uint(f);
    return (u & 0x80000000u) ? ~u : (u | 0x80000000u);
}
__device__ __forceinline__ float unmono32(unsigned m) {
    const unsigned u = (m & 0x80000000u) ? (m & 0x7FFFFFFFu) : ~m;
    return __uint_as_float(u);
}

// ---------------------------------------------------------------------------
// 1024x1024 transpose: out[k][n] = in[n][k]
// ---------------------------------------------------------------------------
__global__ __launch_bounds__(256) void transpose1024(
    const float* __restrict__ in, float* __restrict__ out)
{
    __shared__ float t[32][33];
    const int bx = blockIdx.x * 32, by = blockIdx.y * 32;
    const int tx = threadIdx.x & 31, ty = threadIdx.x >> 5;
    for (int r = ty; r < 32; r += 8)
        t[r][tx] = in[(size_t)(by + r) * DM + bx + tx];
    __syncthreads();
    for (int r = ty; r < 32; r += 8)
        out[(size_t)(bx + r) * DM + by + tx] = t[tx][r];
}

// ---------------------------------------------------------------------------
// Bit-emulated f32 projection (numpy -> OpenBLAS sgemm, Zen/Haswell):
// K-panels (384,320,320); serial ascending-k FMA chain per panel; C += panel;
// then +bias. Scatter to [B,H,L,D]. Wt is W transposed [k][n].  DO NOT TOUCH:
// bit-exactness of Q/K determines top-k selection (absmax margin is 6e-4).
// ---------------------------------------------------------------------------
__global__ __launch_bounds__(256) void proj_emul(
    const float* __restrict__ x, const float* __restrict__ Wt,
    const float* __restrict__ bias, float* __restrict__ outp)
{
    __shared__ float xs[8][DM];   // 32 KB
    const int tid = threadIdx.x;
    const int n   = blockIdx.x * 256 + tid;
    const int m0  = blockIdx.y * 8;

    for (int i = tid; i < 8 * 256; i += 256) {
        const int r = i >> 8, c4 = (i & 255) << 2;
        *(float4*)&xs[r][c4] = *(const float4*)&x[(size_t)(m0 + r) * DM + c4];
    }
    __syncthreads();

    const int kbound[4] = {0, 384, 704, 1024};   // OpenBLAS Zen panel splits

    float S[8] = {0, 0, 0, 0, 0, 0, 0, 0};
#pragma unroll
    for (int p = 0; p < 3; p++) {
        float P[8] = {0, 0, 0, 0, 0, 0, 0, 0};
        for (int k = kbound[p]; k < kbound[p + 1]; k++) {
            const float w = Wt[(size_t)k * DM + n];
#pragma unroll
            for (int m = 0; m < 8; m++) P[m] = fmaf(xs[m][k], w, P[m]);
        }
#pragma unroll
        for (int m = 0; m < 8; m++) S[m] += P[m];   // C += panel (in order)
    }

    const int h = n / HD, d = n % HD;
#pragma unroll
    for (int m = 0; m < 8; m++) {
        const int mm = m0 + m;
        const int b = mm / LL, l = mm % LL;
        outp[(((size_t)b * NH + h) * LL + l) * HD + d] = S[m] + bias[n];
    }
}

// ---------------------------------------------------------------------------
// f32 GEMM for V (MODE 0 scatter) and output projection (MODE 1).
// ---------------------------------------------------------------------------
template <int MODE>
__global__ __launch_bounds__(256) void gemm_f32(
    const float* __restrict__ A, const float* __restrict__ W,
    const float* __restrict__ bias, float* __restrict__ out,
    int M, int N, int K)
{
    __shared__ float As[16][64];
    __shared__ float Bs[16][64];
    const int tid = threadIdx.x;
    const int m0 = blockIdx.y * 64;
    const int n0 = blockIdx.x * 64;
    const int tx = tid & 15, ty = tid >> 4;
    const int lr = tid >> 2, lc = (tid & 3) * 4;

    float acc[4][4] = {};

    for (int k0 = 0; k0 < K; k0 += 16) {
        float4 a4 = *(const float4*)&A[(size_t)(m0 + lr) * K + k0 + lc];
        float4 b4 = *(const float4*)&W[(size_t)(n0 + lr) * K + k0 + lc];
        __syncthreads();
        As[lc + 0][lr] = a4.x; As[lc + 1][lr] = a4.y;
        As[lc + 2][lr] = a4.z; As[lc + 3][lr] = a4.w;
        Bs[lc + 0][lr] = b4.x; Bs[lc + 1][lr] = b4.y;
        Bs[lc + 2][lr] = b4.z; Bs[lc + 3][lr] = b4.w;
        __syncthreads();
#pragma unroll
        for (int kk = 0; kk < 16; kk++) {
            float4 av = *(const float4*)&As[kk][ty * 4];
            float4 bv = *(const float4*)&Bs[kk][tx * 4];
            float a[4] = {av.x, av.y, av.z, av.w};
            float b[4] = {bv.x, bv.y, bv.z, bv.w};
#pragma unroll
            for (int i = 0; i < 4; i++)
#pragma unroll
                for (int j = 0; j < 4; j++)
                    acc[i][j] = fmaf(a[i], b[j], acc[i][j]);
        }
    }

#pragma unroll
    for (int i = 0; i < 4; i++) {
        const int m = m0 + ty * 4 + i;
#pragma unroll
        for (int j = 0; j < 4; j++) {
            const int n = n0 + tx * 4 + j;
            const float v = acc[i][j] + bias[n];
            if (MODE == 0) {
                const int b = m / LL, l = m % LL;
                const int h = n / HD, d = n % HD;
                out[(((size_t)b * NH + h) * LL + l) * HD + d] = v;
            } else {
                out[(size_t)m * N + n] = v;
            }
        }
    }
}

// ---------------------------------------------------------------------------
// Attention v5: block = 8 q-rows of one (b,h), 256 threads = 4 waves.
//  - v5 fix over v3/v4: the 32-tile producer loop is MACRO-EXPANDED with
//    literal tile indices. In v3/v4 `mA[tile]` had a dynamic index at
//    frontend time (huge body -> no early full-unroll) -> allocas never
//    promoted -> 18 GB scratch traffic, VGPR 84. Literal indices let SROA
//    promote mA/mB to VGPRs (rule: runtime-indexed arrays go to scratch).
//  - K staged in LDS, double-buffered 64-key tiles, single barrier per tile.
//  - score chain character-identical (bit-exact, contract off).
//  - selection: exact U-th-largest via monotone-u32 binary search on 32
//    register values/lane; softmax + sparse PV unchanged.
// ---------------------------------------------------------------------------

// bit-exact score chain for tile T (literal), keys = T*64+lane, rows r0/r1
#define SCORE_CHAIN(T)                                                         \
        float axA = 0, ayA = 0, azA = 0, awA = 0;                              \
        float axB = 0, ayB = 0, azB = 0, awB = 0;                              \
        const float* krow = &kt[(T) & 1][lane][0];                             \
        const float* qA = &qsh[r0][0];                                         \
        const float* qB = &qsh[r1][0];                                         \
        _Pragma("unroll")                                                      \
        for (int t = 0; t < 4; t++) {                                          \
            _Pragma("unroll")                                                  \
            for (int sub = 3; sub >= 0; sub--) {                               \
                const int d4 = 4 * t + sub;                                    \
                const float4 kf = *(const float4*)&krow[d4 * 4];               \
                const float4 qa = *(const float4*)&qA[d4 * 4];                 \
                const float4 qb = *(const float4*)&qB[d4 * 4];                 \
                axA = qa.x * kf.x + axA; ayA = qa.y * kf.y + ayA;              \
                azA = qa.z * kf.z + azA; awA = qa.w * kf.w + awA;              \
                axB = qb.x * kf.x + axB; ayB = qb.y * kf.y + ayB;              \
                azB = qb.z * kf.z + azB; awB = qb.w * kf.w + awB;              \
            }                                                                  \
        }                                                                      \
        mA[(T)] = mono32(((axA + ayA) + (azA + awA)) * 0.125f);                \
        mB[(T)] = mono32(((axB + ayB) + (azB + awB)) * 0.125f);

// tiles 0..30: prefetch next tile to regs, compute scores, write next tile,
// ONE barrier (reads kt[T&1] / writes kt[(T&1)^1] are disjoint buffers).
#define TILE_MID(T)                                                            \
    {                                                                          \
        float4 pf0, pf1, pf2, pf3;                                             \
        {                                                                      \
            const float* src = Kb + (size_t)((T) + 1) * 64 * HD;               \
            pf0 = *(const float4*)&src[(size_t)((0 * 256 + tid) >> 4) * HD + ((0 * 256 + tid) & 15) * 4]; \
            pf1 = *(const float4*)&src[(size_t)((1 * 256 + tid) >> 4) * HD + ((1 * 256 + tid) & 15) * 4]; \
            pf2 = *(const float4*)&src[(size_t)((2 * 256 + tid) >> 4) * HD + ((2 * 256 + tid) & 15) * 4]; \
            pf3 = *(const float4*)&src[(size_t)((3 * 256 + tid) >> 4) * HD + ((3 * 256 + tid) & 15) * 4]; \
        }                                                                      \
        SCORE_CHAIN(T)                                                         \
        *(float4*)&kt[((T) & 1) ^ 1][(0 * 256 + tid) >> 4][((0 * 256 + tid) & 15) * 4] = pf0; \
        *(float4*)&kt[((T) & 1) ^ 1][(1 * 256 + tid) >> 4][((1 * 256 + tid) & 15) * 4] = pf1; \
        *(float4*)&kt[((T) & 1) ^ 1][(2 * 256 + tid) >> 4][((2 * 256 + tid) & 15) * 4] = pf2; \
        *(float4*)&kt[((T) & 1) ^ 1][(3 * 256 + tid) >> 4][((3 * 256 + tid) & 15) * 4] = pf3; \
        __syncthreads();                                                       \
    }

#define TILE_LAST(T) { SCORE_CHAIN(T) }

// Per-row selection + softmax + sparse PV. mv = 32 monotone-u32 scores in
// registers (this lane's keys: lane + 64*j). rr = row index in block.
#define ROW_SEL(mv, rr)                                                        \
    {                                                                          \
        unsigned _lo = 0u, _hi = 0xFFFFFFFFu;                                  \
        while (_lo < _hi) {                                                    \
            const unsigned _span = _hi - _lo;                                  \
            const unsigned _mid = _lo + (_span >> 1) + (_span & 1u);           \
            int _c = 0;                                                        \
            _Pragma("unroll")                                                  \
            for (int _j = 0; _j < 32; _j++)                                    \
                _c += (int)__popcll(__ballot(mv[_j] >= _mid));                 \
            if (_c >= U) _lo = _mid; else _hi = _mid - 1u;                     \
        }                                                                      \
        unsigned _mk = 0;                                                      \
        _Pragma("unroll")                                                      \
        for (int _j = 0; _j < 32; _j++)                                        \
            if (mv[_j] >= _lo) _mk = (mv[_j] > _mk) ? mv[_j] : _mk;            \
        _Pragma("unroll")                                                      \
        for (int _off = 32; _off > 0; _off >>= 1) {                            \
            const unsigned _o = __shfl_xor(_mk, _off, 64);                     \
            _mk = (_o > _mk) ? _o : _mk;                                       \
        }                                                                      \
        const float _mx = unmono32(_mk);                                       \
        int _n = 0;                                                            \
        _Pragma("unroll")                                                      \
        for (int _j = 0; _j < 32; _j++) {                                      \
            const bool _p = (mv[_j] >= _lo);                                   \
            const unsigned long long _ball = __ballot(_p);                     \
            if (_p) {                                                          \
                const int _pos = _n + (int)__popcll(_ball & laneLT);           \
                if (_pos < 64) {                                               \
                    kls[rr][_pos] = lane + 64 * _j;                            \
                    wls[rr][_pos] = expf(unmono32(mv[_j]) - _mx);              \
                }                                                              \
            }                                                                  \
            _n += (int)__popcll(_ball);                                        \
        }                                                                      \
        if (_n > 64) _n = 64;                                                  \
        float _dl = (lane < _n) ? wls[rr][lane] : 0.0f;                        \
        _Pragma("unroll")                                                      \
        for (int _off = 32; _off > 0; _off >>= 1)                              \
            _dl += __shfl_xor(_dl, _off, 64);                                  \
        const float _rden = 1.0f / _dl;                                        \
        float _acc = 0.0f;                                                     \
        for (int _c2 = 0; _c2 < _n; _c2++)                                     \
            _acc = fmaf(wls[rr][_c2], Vb[(size_t)kls[rr][_c2] * HD + lane],    \
                        _acc);                                                 \
        ctx[((size_t)b * LL + l0 + rr) * DM + h * HD + lane] = _acc * _rden;   \
    }

__global__ __launch_bounds__(256, 3) void attn_np(
    const float* __restrict__ Qf, const float* __restrict__ Kf,
    const float* __restrict__ Vf, float* __restrict__ ctx, int U)
{
#pragma clang fp contract(off)
    const int tid  = threadIdx.x;
    const int lane = tid & 63;
    const int wv   = tid >> 6;
    const int l0   = blockIdx.x * 8;
    const int h    = blockIdx.y;
    const int b    = blockIdx.z;
    const int bh   = b * NH + h;

    __shared__ float kt[2][64][68];    // 34 KB K tiles (+4 pad per row)
    __shared__ float qsh[8][64];       // 2 KB
    __shared__ float wls[8][64];       // 2 KB
    __shared__ int   kls[8][64];       // 2 KB

    const float* __restrict__ Kb = Kf + (size_t)bh * LL * HD;

    // stage q rows
    if (tid < 128) {
        const int r = tid >> 4, d4 = tid & 15;
        *(float4*)&qsh[r][d4 * 4] =
            *(const float4*)&Qf[((size_t)bh * LL + l0 + r) * HD + d4 * 4];
    }
    // stage K tile 0 (64 rows x 16 float4; 4 float4 per thread, coalesced)
#pragma unroll
    for (int i = 0; i < 4; i++) {
        const int idx = i * 256 + tid;
        *(float4*)&kt[0][idx >> 4][(idx & 15) * 4] =
            *(const float4*)&Kb[(size_t)(idx >> 4) * HD + (idx & 15) * 4];
    }
    __syncthreads();

    const int r0 = wv * 2, r1 = r0 + 1;

    // per-lane scores (monotone u32), 32 tiles x 2 rows — registers
    unsigned mA[32], mB[32];

    TILE_MID(0)  TILE_MID(1)  TILE_MID(2)  TILE_MID(3)
    TILE_MID(4)  TILE_MID(5)  TILE_MID(6)  TILE_MID(7)
    TILE_MID(8)  TILE_MID(9)  TILE_MID(10) TILE_MID(11)
    TILE_MID(12) TILE_MID(13) TILE_MID(14) TILE_MID(15)
    TILE_MID(16) TILE_MID(17) TILE_MID(18) TILE_MID(19)
    TILE_MID(20) TILE_MID(21) TILE_MID(22) TILE_MID(23)
    TILE_MID(24) TILE_MID(25) TILE_MID(26) TILE_MID(27)
    TILE_MID(28) TILE_MID(29) TILE_MID(30)
    TILE_LAST(31)

    // ---- per-row selection + softmax + PV (wave handles rows r0, r1) ----
    // No barrier needed: selection uses registers + this wave's own
    // wls/kls rows only.
    const unsigned long long laneLT = (1ull << lane) - 1ull;
    const float* __restrict__ Vb = Vf + (size_t)bh * LL * HD;

    ROW_SEL(mA, r0);
    ROW_SEL(mB, r1);
}

// ---------------------------------------------------------------------------
extern "C" void kernel_launch(void* const* d_in, const int* in_sizes, int n_in,
                              void* d_out, int out_size, void* d_ws, size_t ws_size,
                              hipStream_t stream)
{
    const float* x  = (const float*)d_in[0];
    const float* Wq = (const float*)d_in[1];
    const float* bq = (const float*)d_in[2];
    const float* Wk = (const float*)d_in[3];
    const float* bk = (const float*)d_in[4];
    const float* Wv = (const float*)d_in[5];
    const float* bv = (const float*)d_in[6];
    const float* Wo = (const float*)d_in[7];
    const float* bo = (const float*)d_in[8];
    float* out = (float*)d_out;

    const size_t E = (size_t)BB * NH * LL * HD;   // 4M elements
    float* Wt1 = (float*)d_ws;                    // 4 MB
    float* Wt2 = Wt1 + (size_t)DM * DM;           // 4 MB
    float* Qf  = Wt2 + (size_t)DM * DM;           // 16 MB
    float* Kf  = Qf + E;                          // 16 MB
    float* Vf  = Kf + E;                          // 16 MB
    float* ctx = Vf + E;                          // 16 MB   (72 MB total)

    int U = (int)(5.0 * log((double)LL));
    if (U > LL) U = LL;

    const int M = BB * LL;  // 4096
    dim3 blk(256);
    dim3 gT(DM / 32, DM / 32);
    dim3 gP(DM / 256, M / 8);
    dim3 g64(DM / 64, M / 64);

    hipLaunchKernelGGL(transpose1024, gT, blk, 0, stream, Wq, Wt1);
    hipLaunchKernelGGL(transpose1024, gT, blk, 0, stream, Wk, Wt2);
    hipLaunchKernelGGL(proj_emul, gP, blk, 0, stream, x, Wt1, bq, Qf);
    hipLaunchKernelGGL(proj_emul, gP, blk, 0, stream, x, Wt2, bk, Kf);
    hipLaunchKernelGGL((gemm_f32<0>), g64, blk, 0, stream, x, Wv, bv, Vf, M, DM, DM);
    hipLaunchKernelGGL(attn_np, dim3(LL / 8, NH, BB), blk, 0, stream, Qf, Kf, Vf, ctx, U);
    hipLaunchKernelGGL((gemm_f32<1>), g64, blk, 0, stream, ctx, Wo, bo, out, M, DM, DM);
}

// Round 6
// 5285.180 us; speedup vs baseline: 1.1514x; 1.1514x over previous
//
#include <hip/hip_runtime.h>
#include <math.h>

#define BB 2
#define LL 2048
#define DM 1024
#define NH 16
#define HD 64

__device__ __forceinline__ unsigned mono32(float f) {
    unsigned u = __float_as_uint(f);
    return (u & 0x80000000u) ? ~u : (u | 0x80000000u);
}
__device__ __forceinline__ float unmono32(unsigned m) {
    const unsigned u = (m & 0x80000000u) ? (m & 0x7FFFFFFFu) : ~m;
    return __uint_as_float(u);
}

// ---------------------------------------------------------------------------
// 1024x1024 transpose: out[k][n] = in[n][k]
// ---------------------------------------------------------------------------
__global__ __launch_bounds__(256) void transpose1024(
    const float* __restrict__ in, float* __restrict__ out)
{
    __shared__ float t[32][33];
    const int bx = blockIdx.x * 32, by = blockIdx.y * 32;
    const int tx = threadIdx.x & 31, ty = threadIdx.x >> 5;
    for (int r = ty; r < 32; r += 8)
        t[r][tx] = in[(size_t)(by + r) * DM + bx + tx];
    __syncthreads();
    for (int r = ty; r < 32; r += 8)
        out[(size_t)(bx + r) * DM + by + tx] = t[tx][r];
}

// ---------------------------------------------------------------------------
// Bit-emulated f32 projection (numpy -> OpenBLAS sgemm, Zen/Haswell):
// K-panels (384,320,320); serial ascending-k FMA chain per panel; C += panel;
// then +bias. Scatter to [B,H,L,D]. Wt is W transposed [k][n].  DO NOT TOUCH:
// bit-exactness of Q/K determines top-k selection (absmax margin is 6e-4).
// ---------------------------------------------------------------------------
__global__ __launch_bounds__(256) void proj_emul(
    const float* __restrict__ x, const float* __restrict__ Wt,
    const float* __restrict__ bias, float* __restrict__ outp)
{
    __shared__ float xs[8][DM];   // 32 KB
    const int tid = threadIdx.x;
    const int n   = blockIdx.x * 256 + tid;
    const int m0  = blockIdx.y * 8;

    for (int i = tid; i < 8 * 256; i += 256) {
        const int r = i >> 8, c4 = (i & 255) << 2;
        *(float4*)&xs[r][c4] = *(const float4*)&x[(size_t)(m0 + r) * DM + c4];
    }
    __syncthreads();

    const int kbound[4] = {0, 384, 704, 1024};   // OpenBLAS Zen panel splits

    float S[8] = {0, 0, 0, 0, 0, 0, 0, 0};
#pragma unroll
    for (int p = 0; p < 3; p++) {
        float P[8] = {0, 0, 0, 0, 0, 0, 0, 0};
        for (int k = kbound[p]; k < kbound[p + 1]; k++) {
            const float w = Wt[(size_t)k * DM + n];
#pragma unroll
            for (int m = 0; m < 8; m++) P[m] = fmaf(xs[m][k], w, P[m]);
        }
#pragma unroll
        for (int m = 0; m < 8; m++) S[m] += P[m];   // C += panel (in order)
    }

    const int h = n / HD, d = n % HD;
#pragma unroll
    for (int m = 0; m < 8; m++) {
        const int mm = m0 + m;
        const int b = mm / LL, l = mm % LL;
        outp[(((size_t)b * NH + h) * LL + l) * HD + d] = S[m] + bias[n];
    }
}

// ---------------------------------------------------------------------------
// f32 GEMM for V (MODE 0 scatter) and output projection (MODE 1).
// ---------------------------------------------------------------------------
template <int MODE>
__global__ __launch_bounds__(256) void gemm_f32(
    const float* __restrict__ A, const float* __restrict__ W,
    const float* __restrict__ bias, float* __restrict__ out,
    int M, int N, int K)
{
    __shared__ float As[16][64];
    __shared__ float Bs[16][64];
    const int tid = threadIdx.x;
    const int m0 = blockIdx.y * 64;
    const int n0 = blockIdx.x * 64;
    const int tx = tid & 15, ty = tid >> 4;
    const int lr = tid >> 2, lc = (tid & 3) * 4;

    float acc[4][4] = {};

    for (int k0 = 0; k0 < K; k0 += 16) {
        float4 a4 = *(const float4*)&A[(size_t)(m0 + lr) * K + k0 + lc];
        float4 b4 = *(const float4*)&W[(size_t)(n0 + lr) * K + k0 + lc];
        __syncthreads();
        As[lc + 0][lr] = a4.x; As[lc + 1][lr] = a4.y;
        As[lc + 2][lr] = a4.z; As[lc + 3][lr] = a4.w;
        Bs[lc + 0][lr] = b4.x; Bs[lc + 1][lr] = b4.y;
        Bs[lc + 2][lr] = b4.z; Bs[lc + 3][lr] = b4.w;
        __syncthreads();
#pragma unroll
        for (int kk = 0; kk < 16; kk++) {
            float4 av = *(const float4*)&As[kk][ty * 4];
            float4 bv = *(const float4*)&Bs[kk][tx * 4];
            float a[4] = {av.x, av.y, av.z, av.w};
            float b[4] = {bv.x, bv.y, bv.z, bv.w};
#pragma unroll
            for (int i = 0; i < 4; i++)
#pragma unroll
                for (int j = 0; j < 4; j++)
                    acc[i][j] = fmaf(a[i], b[j], acc[i][j]);
        }
    }

#pragma unroll
    for (int i = 0; i < 4; i++) {
        const int m = m0 + ty * 4 + i;
#pragma unroll
        for (int j = 0; j < 4; j++) {
            const int n = n0 + tx * 4 + j;
            const float v = acc[i][j] + bias[n];
            if (MODE == 0) {
                const int b = m / LL, l = m % LL;
                const int h = n / HD, d = n % HD;
                out[(((size_t)b * NH + h) * LL + l) * HD + d] = v;
            } else {
                out[(size_t)m * N + n] = v;
            }
        }
    }
}

// ---------------------------------------------------------------------------
// Attention v6: block = 8 q-rows of one (b,h), 256 threads = 4 waves.
//  - v6 fix over v3/v4/v5: scores live in 64 NAMED SCALAR variables
//    (mA0..mA31, mB0..mB31) via token-pasting macros. v3-v5 used unsigned[32]
//    arrays; the compiler NEVER promoted those allocas (VGPR stuck at 84,
//    ~18 GB scratch traffic, attn ~5.2 ms) regardless of literal indexing.
//    Named scalars are SSA values -> guaranteed VGPR residency, no alloca.
//  - K staged in LDS, double-buffered 64-key tiles, single barrier per tile.
//  - score chain + selection arithmetic token-identical (bit-exact,
//    contract off): exact U-th-largest via monotone-u32 binary search,
//    softmax + sparse PV unchanged.
// ---------------------------------------------------------------------------

#define CAT_(a, b) a##b
#define CAT(a, b) CAT_(a, b)

#define REP32P(X, P)                                                           \
    X(P, 0)  X(P, 1)  X(P, 2)  X(P, 3)  X(P, 4)  X(P, 5)  X(P, 6)  X(P, 7)     \
    X(P, 8)  X(P, 9)  X(P, 10) X(P, 11) X(P, 12) X(P, 13) X(P, 14) X(P, 15)    \
    X(P, 16) X(P, 17) X(P, 18) X(P, 19) X(P, 20) X(P, 21) X(P, 22) X(P, 23)    \
    X(P, 24) X(P, 25) X(P, 26) X(P, 27) X(P, 28) X(P, 29) X(P, 30) X(P, 31)

#define DECLV(P, J) unsigned CAT(P, J) = 0u;

// bit-exact score chain for tile T (literal), keys = T*64+lane, rows r0/r1
#define SCORE_CHAIN(T)                                                         \
        float axA = 0, ayA = 0, azA = 0, awA = 0;                              \
        float axB = 0, ayB = 0, azB = 0, awB = 0;                              \
        const float* krow = &kt[(T) & 1][lane][0];                             \
        const float* qA = &qsh[r0][0];                                         \
        const float* qB = &qsh[r1][0];                                         \
        _Pragma("unroll")                                                      \
        for (int t = 0; t < 4; t++) {                                          \
            _Pragma("unroll")                                                  \
            for (int sub = 3; sub >= 0; sub--) {                               \
                const int d4 = 4 * t + sub;                                    \
                const float4 kf = *(const float4*)&krow[d4 * 4];               \
                const float4 qa = *(const float4*)&qA[d4 * 4];                 \
                const float4 qb = *(const float4*)&qB[d4 * 4];                 \
                axA = qa.x * kf.x + axA; ayA = qa.y * kf.y + ayA;              \
                azA = qa.z * kf.z + azA; awA = qa.w * kf.w + awA;              \
                axB = qb.x * kf.x + axB; ayB = qb.y * kf.y + ayB;              \
                azB = qb.z * kf.z + azB; awB = qb.w * kf.w + awB;              \
            }                                                                  \
        }                                                                      \
        CAT(mA, T) = mono32(((axA + ayA) + (azA + awA)) * 0.125f);             \
        CAT(mB, T) = mono32(((axB + ayB) + (azB + awB)) * 0.125f);

// tiles 0..30: prefetch next tile to regs, compute scores, write next tile,
// ONE barrier (reads kt[T&1] / writes kt[(T&1)^1] are disjoint buffers).
#define TILE_MID(T)                                                            \
    {                                                                          \
        float4 pf0, pf1, pf2, pf3;                                             \
        {                                                                      \
            const float* src = Kb + (size_t)((T) + 1) * 64 * HD;               \
            pf0 = *(const float4*)&src[(size_t)((0 * 256 + tid) >> 4) * HD + ((0 * 256 + tid) & 15) * 4]; \
            pf1 = *(const float4*)&src[(size_t)((1 * 256 + tid) >> 4) * HD + ((1 * 256 + tid) & 15) * 4]; \
            pf2 = *(const float4*)&src[(size_t)((2 * 256 + tid) >> 4) * HD + ((2 * 256 + tid) & 15) * 4]; \
            pf3 = *(const float4*)&src[(size_t)((3 * 256 + tid) >> 4) * HD + ((3 * 256 + tid) & 15) * 4]; \
        }                                                                      \
        SCORE_CHAIN(T)                                                         \
        *(float4*)&kt[((T) & 1) ^ 1][(0 * 256 + tid) >> 4][((0 * 256 + tid) & 15) * 4] = pf0; \
        *(float4*)&kt[((T) & 1) ^ 1][(1 * 256 + tid) >> 4][((1 * 256 + tid) & 15) * 4] = pf1; \
        *(float4*)&kt[((T) & 1) ^ 1][(2 * 256 + tid) >> 4][((2 * 256 + tid) & 15) * 4] = pf2; \
        *(float4*)&kt[((T) & 1) ^ 1][(3 * 256 + tid) >> 4][((3 * 256 + tid) & 15) * 4] = pf3; \
        __syncthreads();                                                       \
    }

#define TILE_LAST(T) { SCORE_CHAIN(T) }

// ---- selection pieces over named scalars (expanded inside ROW_SEL scope;
//      _mid/_lo/_mk/_c/_n/_mx/_rr are locals of that scope) ----
#define SEL_CNT(P, J)                                                          \
    _c += (int)__popcll(__ballot(CAT(P, J) >= _mid));

#define SEL_MAX(P, J)                                                          \
    if (CAT(P, J) >= _lo) _mk = (CAT(P, J) > _mk) ? CAT(P, J) : _mk;

#define SEL_CPT(P, J)                                                          \
    {                                                                          \
        const bool _p = (CAT(P, J) >= _lo);                                    \
        const unsigned long long _ball = __ballot(_p);                         \
        if (_p) {                                                              \
            const int _pos = _n + (int)__popcll(_ball & laneLT);               \
            if (_pos < 64) {                                                   \
                kls[_rr][_pos] = lane + 64 * (J);                              \
                wls[_rr][_pos] = expf(unmono32(CAT(P, J)) - _mx);              \
            }                                                                  \
        }                                                                      \
        _n += (int)__popcll(_ball);                                            \
    }

// Per-row selection + softmax + sparse PV over named scalars with prefix P.
#define ROW_SEL(P, rr)                                                         \
    {                                                                          \
        const int _rr = (rr);                                                  \
        unsigned _lo = 0u, _hi = 0xFFFFFFFFu;                                  \
        while (_lo < _hi) {                                                    \
            const unsigned _span = _hi - _lo;                                  \
            const unsigned _mid = _lo + (_span >> 1) + (_span & 1u);           \
            int _c = 0;                                                        \
            REP32P(SEL_CNT, P)                                                 \
            if (_c >= U) _lo = _mid; else _hi = _mid - 1u;                     \
        }                                                                      \
        unsigned _mk = 0;                                                      \
        REP32P(SEL_MAX, P)                                                     \
        _Pragma("unroll")                                                      \
        for (int _off = 32; _off > 0; _off >>= 1) {                            \
            const unsigned _o = __shfl_xor(_mk, _off, 64);                     \
            _mk = (_o > _mk) ? _o : _mk;                                       \
        }                                                                      \
        const float _mx = unmono32(_mk);                                       \
        int _n = 0;                                                            \
        REP32P(SEL_CPT, P)                                                     \
        if (_n > 64) _n = 64;                                                  \
        float _dl = (lane < _n) ? wls[_rr][lane] : 0.0f;                       \
        _Pragma("unroll")                                                      \
        for (int _off = 32; _off > 0; _off >>= 1)                              \
            _dl += __shfl_xor(_dl, _off, 64);                                  \
        const float _rden = 1.0f / _dl;                                        \
        float _acc = 0.0f;                                                     \
        for (int _c2 = 0; _c2 < _n; _c2++)                                     \
            _acc = fmaf(wls[_rr][_c2], Vb[(size_t)kls[_rr][_c2] * HD + lane],  \
                        _acc);                                                 \
        ctx[((size_t)b * LL + l0 + _rr) * DM + h * HD + lane] = _acc * _rden;  \
    }

__global__ __launch_bounds__(256, 3) void attn_np(
    const float* __restrict__ Qf, const float* __restrict__ Kf,
    const float* __restrict__ Vf, float* __restrict__ ctx, int U)
{
#pragma clang fp contract(off)
    const int tid  = threadIdx.x;
    const int lane = tid & 63;
    const int wv   = tid >> 6;
    const int l0   = blockIdx.x * 8;
    const int h    = blockIdx.y;
    const int b    = blockIdx.z;
    const int bh   = b * NH + h;

    __shared__ float kt[2][64][68];    // 34 KB K tiles (+4 pad per row)
    __shared__ float qsh[8][64];       // 2 KB
    __shared__ float wls[8][64];       // 2 KB
    __shared__ int   kls[8][64];       // 2 KB

    const float* __restrict__ Kb = Kf + (size_t)bh * LL * HD;

    // stage q rows
    if (tid < 128) {
        const int r = tid >> 4, d4 = tid & 15;
        *(float4*)&qsh[r][d4 * 4] =
            *(const float4*)&Qf[((size_t)bh * LL + l0 + r) * HD + d4 * 4];
    }
    // stage K tile 0 (64 rows x 16 float4; 4 float4 per thread, coalesced)
#pragma unroll
    for (int i = 0; i < 4; i++) {
        const int idx = i * 256 + tid;
        *(float4*)&kt[0][idx >> 4][(idx & 15) * 4] =
            *(const float4*)&Kb[(size_t)(idx >> 4) * HD + (idx & 15) * 4];
    }
    __syncthreads();

    const int r0 = wv * 2, r1 = r0 + 1;

    // per-lane scores (monotone u32): 64 NAMED scalars -> guaranteed VGPRs
    REP32P(DECLV, mA)
    REP32P(DECLV, mB)

    TILE_MID(0)  TILE_MID(1)  TILE_MID(2)  TILE_MID(3)
    TILE_MID(4)  TILE_MID(5)  TILE_MID(6)  TILE_MID(7)
    TILE_MID(8)  TILE_MID(9)  TILE_MID(10) TILE_MID(11)
    TILE_MID(12) TILE_MID(13) TILE_MID(14) TILE_MID(15)
    TILE_MID(16) TILE_MID(17) TILE_MID(18) TILE_MID(19)
    TILE_MID(20) TILE_MID(21) TILE_MID(22) TILE_MID(23)
    TILE_MID(24) TILE_MID(25) TILE_MID(26) TILE_MID(27)
    TILE_MID(28) TILE_MID(29) TILE_MID(30)
    TILE_LAST(31)

    // ---- per-row selection + softmax + PV (wave handles rows r0, r1) ----
    // No barrier needed: selection uses registers + this wave's own
    // wls/kls rows only.
    const unsigned long long laneLT = (1ull << lane) - 1ull;
    const float* __restrict__ Vb = Vf + (size_t)bh * LL * HD;

    ROW_SEL(mA, r0);
    ROW_SEL(mB, r1);
}

// ---------------------------------------------------------------------------
extern "C" void kernel_launch(void* const* d_in, const int* in_sizes, int n_in,
                              void* d_out, int out_size, void* d_ws, size_t ws_size,
                              hipStream_t stream)
{
    const float* x  = (const float*)d_in[0];
    const float* Wq = (const float*)d_in[1];
    const float* bq = (const float*)d_in[2];
    const float* Wk = (const float*)d_in[3];
    const float* bk = (const float*)d_in[4];
    const float* Wv = (const float*)d_in[5];
    const float* bv = (const float*)d_in[6];
    const float* Wo = (const float*)d_in[7];
    const float* bo = (const float*)d_in[8];
    float* out = (float*)d_out;

    const size_t E = (size_t)BB * NH * LL * HD;   // 4M elements
    float* Wt1 = (float*)d_ws;                    // 4 MB
    float* Wt2 = Wt1 + (size_t)DM * DM;           // 4 MB
    float* Qf  = Wt2 + (size_t)DM * DM;           // 16 MB
    float* Kf  = Qf + E;                          // 16 MB
    float* Vf  = Kf + E;                          // 16 MB
    float* ctx = Vf + E;                          // 16 MB   (72 MB total)

    int U = (int)(5.0 * log((double)LL));
    if (U > LL) U = LL;

    const int M = BB * LL;  // 4096
    dim3 blk(256);
    dim3 gT(DM / 32, DM / 32);
    dim3 gP(DM / 256, M / 8);
    dim3 g64(DM / 64, M / 64);

    hipLaunchKernelGGL(transpose1024, gT, blk, 0, stream, Wq, Wt1);
    hipLaunchKernelGGL(transpose1024, gT, blk, 0, stream, Wk, Wt2);
    hipLaunchKernelGGL(proj_emul, gP, blk, 0, stream, x, Wt1, bq, Qf);
    hipLaunchKernelGGL(proj_emul, gP, blk, 0, stream, x, Wt2, bk, Kf);
    hipLaunchKernelGGL((gemm_f32<0>), g64, blk, 0, stream, x, Wv, bv, Vf, M, DM, DM);
    hipLaunchKernelGGL(attn_np, dim3(LL / 8, NH, BB), blk, 0, stream, Qf, Kf, Vf, ctx, U);
    hipLaunchKernelGGL((gemm_f32<1>), g64, blk, 0, stream, ctx, Wo, bo, out, M, DM, DM);
}

// Round 7
// 1947.825 us; speedup vs baseline: 3.1243x; 2.7134x over previous
//
#include <hip/hip_runtime.h>
#include <math.h>

#define BB 2
#define LL 2048
#define DM 1024
#define NH 16
#define HD 64

__device__ __forceinline__ unsigned mono32(float f) {
    unsigned u = __float_as_uint(f);
    return (u & 0x80000000u) ? ~u : (u | 0x80000000u);
}
__device__ __forceinline__ float unmono32(unsigned m) {
    const unsigned u = (m & 0x80000000u) ? (m & 0x7FFFFFFFu) : ~m;
    return __uint_as_float(u);
}

// ---------------------------------------------------------------------------
// 1024x1024 transpose: out[k][n] = in[n][k]
// ---------------------------------------------------------------------------
__global__ __launch_bounds__(256) void transpose1024(
    const float* __restrict__ in, float* __restrict__ out)
{
    __shared__ float t[32][33];
    const int bx = blockIdx.x * 32, by = blockIdx.y * 32;
    const int tx = threadIdx.x & 31, ty = threadIdx.x >> 5;
    for (int r = ty; r < 32; r += 8)
        t[r][tx] = in[(size_t)(by + r) * DM + bx + tx];
    __syncthreads();
    for (int r = ty; r < 32; r += 8)
        out[(size_t)(bx + r) * DM + by + tx] = t[tx][r];
}

// ---------------------------------------------------------------------------
// Bit-emulated f32 projection (numpy -> OpenBLAS sgemm, Zen/Haswell):
// K-panels (384,320,320); serial ascending-k FMA chain per panel; C += panel;
// then +bias. Scatter to [B,H,L,D]. Wt is W transposed [k][n].  DO NOT TOUCH:
// bit-exactness of Q/K determines top-k selection (absmax margin is 6e-4).
// ---------------------------------------------------------------------------
__global__ __launch_bounds__(256) void proj_emul(
    const float* __restrict__ x, const float* __restrict__ Wt,
    const float* __restrict__ bias, float* __restrict__ outp)
{
    __shared__ float xs[8][DM];   // 32 KB
    const int tid = threadIdx.x;
    const int n   = blockIdx.x * 256 + tid;
    const int m0  = blockIdx.y * 8;

    for (int i = tid; i < 8 * 256; i += 256) {
        const int r = i >> 8, c4 = (i & 255) << 2;
        *(float4*)&xs[r][c4] = *(const float4*)&x[(size_t)(m0 + r) * DM + c4];
    }
    __syncthreads();

    const int kbound[4] = {0, 384, 704, 1024};   // OpenBLAS Zen panel splits

    float S[8] = {0, 0, 0, 0, 0, 0, 0, 0};
#pragma unroll
    for (int p = 0; p < 3; p++) {
        float P[8] = {0, 0, 0, 0, 0, 0, 0, 0};
        for (int k = kbound[p]; k < kbound[p + 1]; k++) {
            const float w = Wt[(size_t)k * DM + n];
#pragma unroll
            for (int m = 0; m < 8; m++) P[m] = fmaf(xs[m][k], w, P[m]);
        }
#pragma unroll
        for (int m = 0; m < 8; m++) S[m] += P[m];   // C += panel (in order)
    }

    const int h = n / HD, d = n % HD;
#pragma unroll
    for (int m = 0; m < 8; m++) {
        const int mm = m0 + m;
        const int b = mm / LL, l = mm % LL;
        outp[(((size_t)b * NH + h) * LL + l) * HD + d] = S[m] + bias[n];
    }
}

// ---------------------------------------------------------------------------
// f32 GEMM for V (MODE 0 scatter) and output projection (MODE 1).
// ---------------------------------------------------------------------------
template <int MODE>
__global__ __launch_bounds__(256) void gemm_f32(
    const float* __restrict__ A, const float* __restrict__ W,
    const float* __restrict__ bias, float* __restrict__ out,
    int M, int N, int K)
{
    __shared__ float As[16][64];
    __shared__ float Bs[16][64];
    const int tid = threadIdx.x;
    const int m0 = blockIdx.y * 64;
    const int n0 = blockIdx.x * 64;
    const int tx = tid & 15, ty = tid >> 4;
    const int lr = tid >> 2, lc = (tid & 3) * 4;

    float acc[4][4] = {};

    for (int k0 = 0; k0 < K; k0 += 16) {
        float4 a4 = *(const float4*)&A[(size_t)(m0 + lr) * K + k0 + lc];
        float4 b4 = *(const float4*)&W[(size_t)(n0 + lr) * K + k0 + lc];
        __syncthreads();
        As[lc + 0][lr] = a4.x; As[lc + 1][lr] = a4.y;
        As[lc + 2][lr] = a4.z; As[lc + 3][lr] = a4.w;
        Bs[lc + 0][lr] = b4.x; Bs[lc + 1][lr] = b4.y;
        Bs[lc + 2][lr] = b4.z; Bs[lc + 3][lr] = b4.w;
        __syncthreads();
#pragma unroll
        for (int kk = 0; kk < 16; kk++) {
            float4 av = *(const float4*)&As[kk][ty * 4];
            float4 bv = *(const float4*)&Bs[kk][tx * 4];
            float a[4] = {av.x, av.y, av.z, av.w};
            float b[4] = {bv.x, bv.y, bv.z, bv.w};
#pragma unroll
            for (int i = 0; i < 4; i++)
#pragma unroll
                for (int j = 0; j < 4; j++)
                    acc[i][j] = fmaf(a[i], b[j], acc[i][j]);
        }
    }

#pragma unroll
    for (int i = 0; i < 4; i++) {
        const int m = m0 + ty * 4 + i;
#pragma unroll
        for (int j = 0; j < 4; j++) {
            const int n = n0 + tx * 4 + j;
            const float v = acc[i][j] + bias[n];
            if (MODE == 0) {
                const int b = m / LL, l = m % LL;
                const int h = n / HD, d = n % HD;
                out[(((size_t)b * NH + h) * LL + l) * HD + d] = v;
            } else {
                out[(size_t)m * N + n] = v;
            }
        }
    }
}

// ---------------------------------------------------------------------------
// Attention v7: SPLIT into score_np (producer) + select_np (consumer).
//
// History: v3-v6 tried to keep 64 per-lane scores live across the whole
// 32-tile producer (lambda / macro array / literal-index array / 64 named
// SSA scalars). ALL spilled identically (VGPR 84, ~16 GB scratch traffic,
// attn ~4.6-5.2 ms): regalloc cannot keep a 64-reg live range across the
// producer's ~80-reg working set under any launch-bounds cap. R0's variant
// (scores via LDS, mv[32] born AFTER the producer) ran clean (VGPR 132,
// zero scratch). Conclusion: the long live range is structural; remove it.
//
// score_np: proven producer (LDS double-buffered K tiles, bit-exact
//   einsum-SSE3 chain, single barrier per tile), each score stored
//   IMMEDIATELY to a global scores buffer as monotone u32 (coalesced).
//   No per-thread arrays -> low VGPR, LDS 36 KB -> 4 blocks/CU.
// select_np: R0's proven consumer verbatim; mv[32] loaded from the scores
//   buffer (coalesced, short live range -> registers), exact U-th-largest
//   binary search, softmax + sparse PV, ctx write.
// Chunked by up-to-8 (b,h) panels (128 MB scores buffer, sized from
// ws_size); A/B alternate on the stream (stream order = dependency).
// ---------------------------------------------------------------------------
__global__ __launch_bounds__(256) void score_np(
    const float* __restrict__ Qf, const float* __restrict__ Kf,
    unsigned* __restrict__ scw, int bh0)
{
#pragma clang fp contract(off)
    const int tid  = threadIdx.x;
    const int lane = tid & 63;
    const int wv   = tid >> 6;
    const int l0   = blockIdx.x * 8;
    const int bhl  = blockIdx.y;
    const int bh   = bh0 + bhl;

    __shared__ float kt[2][64][68];    // 34 KB K tiles (+4 pad per row)
    __shared__ float qsh[8][64];       // 2 KB

    const float* __restrict__ Kb = Kf + (size_t)bh * LL * HD;

    // stage q rows
    if (tid < 128) {
        const int r = tid >> 4, d4 = tid & 15;
        *(float4*)&qsh[r][d4 * 4] =
            *(const float4*)&Qf[((size_t)bh * LL + l0 + r) * HD + d4 * 4];
    }
    // stage K tile 0 (64 rows x 16 float4; coalesced)
#pragma unroll
    for (int i = 0; i < 4; i++) {
        const int idx = i * 256 + tid;
        *(float4*)&kt[0][idx >> 4][(idx & 15) * 4] =
            *(const float4*)&Kb[(size_t)(idx >> 4) * HD + (idx & 15) * 4];
    }
    __syncthreads();

    const int r0 = wv * 2, r1 = r0 + 1;
    unsigned* __restrict__ s0 = scw + ((size_t)bhl * LL + l0 + r0) * LL;
    unsigned* __restrict__ s1 = scw + ((size_t)bhl * LL + l0 + r1) * LL;

    for (int tile = 0; tile < 32; tile++) {
        const int buf = tile & 1;
        float4 pf0, pf1, pf2, pf3;
        if (tile < 31) {
            const float* src = Kb + (size_t)(tile + 1) * 64 * HD;
            pf0 = *(const float4*)&src[(size_t)((0 * 256 + tid) >> 4) * HD + ((0 * 256 + tid) & 15) * 4];
            pf1 = *(const float4*)&src[(size_t)((1 * 256 + tid) >> 4) * HD + ((1 * 256 + tid) & 15) * 4];
            pf2 = *(const float4*)&src[(size_t)((2 * 256 + tid) >> 4) * HD + ((2 * 256 + tid) & 15) * 4];
            pf3 = *(const float4*)&src[(size_t)((3 * 256 + tid) >> 4) * HD + ((3 * 256 + tid) & 15) * 4];
        }

        // scores for key = tile*64 + lane, rows r0 and r1 (bit-exact chain)
        float axA = 0, ayA = 0, azA = 0, awA = 0;
        float axB = 0, ayB = 0, azB = 0, awB = 0;
        const float* krow = &kt[buf][lane][0];
        const float* qA = &qsh[r0][0];
        const float* qB = &qsh[r1][0];
#pragma unroll
        for (int t = 0; t < 4; t++) {
#pragma unroll
            for (int sub = 3; sub >= 0; sub--) {
                const int d4 = 4 * t + sub;
                const float4 kf = *(const float4*)&krow[d4 * 4];
                const float4 qa = *(const float4*)&qA[d4 * 4];
                const float4 qb = *(const float4*)&qB[d4 * 4];
                axA = qa.x * kf.x + axA; ayA = qa.y * kf.y + ayA;
                azA = qa.z * kf.z + azA; awA = qa.w * kf.w + awA;
                axB = qb.x * kf.x + axB; ayB = qb.y * kf.y + ayB;
                azB = qb.z * kf.z + azB; awB = qb.w * kf.w + awB;
            }
        }
        // immediate coalesced store (lane-consecutive u32), no live range
        s0[tile * 64 + lane] = mono32(((axA + ayA) + (azA + awA)) * 0.125f);
        s1[tile * 64 + lane] = mono32(((axB + ayB) + (azB + awB)) * 0.125f);

        if (tile < 31) {
            // single barrier per tile: reads kt[buf] / writes kt[buf^1]
            // are disjoint buffers (verified correct v3-v6).
            *(float4*)&kt[buf ^ 1][(0 * 256 + tid) >> 4][((0 * 256 + tid) & 15) * 4] = pf0;
            *(float4*)&kt[buf ^ 1][(1 * 256 + tid) >> 4][((1 * 256 + tid) & 15) * 4] = pf1;
            *(float4*)&kt[buf ^ 1][(2 * 256 + tid) >> 4][((2 * 256 + tid) & 15) * 4] = pf2;
            *(float4*)&kt[buf ^ 1][(3 * 256 + tid) >> 4][((3 * 256 + tid) & 15) * 4] = pf3;
            __syncthreads();
        }
    }
}

__global__ __launch_bounds__(256) void select_np(
    const unsigned* __restrict__ scw, const float* __restrict__ Vf,
    float* __restrict__ ctx, int U, int bh0)
{
#pragma clang fp contract(off)
    const int tid  = threadIdx.x;
    const int lane = tid & 63;
    const int wv   = tid >> 6;
    const int l0   = blockIdx.x * 8;
    const int bhl  = blockIdx.y;
    const int bh   = bh0 + bhl;
    const int b    = bh / NH;
    const int h    = bh % NH;

    __shared__ float wls[8][64];       // 2 KB
    __shared__ int   kls[8][64];       // 2 KB

    const unsigned long long laneLT = (1ull << lane) - 1ull;
    const float* __restrict__ Vb = Vf + (size_t)bh * LL * HD;

#pragma unroll
    for (int rr8 = 0; rr8 < 2; rr8++) {
        const int rr = wv * 2 + rr8;
        const unsigned* __restrict__ srow =
            scw + ((size_t)bhl * LL + l0 + rr) * LL;

        // own-lane scores, coalesced load; SHORT live range -> registers
        // (R0-proven promotable shape: mv born here, dies end of this block)
        unsigned mv[32];
#pragma unroll
        for (int j = 0; j < 32; j++) mv[j] = srow[lane + 64 * j];

        // exact U-th-largest key (largest T with count(>=T) >= U)
        unsigned lo = 0u, hi = 0xFFFFFFFFu;
        while (lo < hi) {
            const unsigned span = hi - lo;
            const unsigned mid = lo + (span >> 1) + (span & 1u);
            int c = 0;
#pragma unroll
            for (int j = 0; j < 32; j++)
                c += (int)__popcll(__ballot(mv[j] >= mid));
            if (c >= U) lo = mid; else hi = mid - 1u;
        }

        // max kept (reduce in key domain; lanes w/o kept contribute 0)
        unsigned mk = 0;
#pragma unroll
        for (int j = 0; j < 32; j++)
            if (mv[j] >= lo) mk = (mv[j] > mk) ? mv[j] : mk;
#pragma unroll
        for (int off = 32; off > 0; off >>= 1) {
            const unsigned o = __shfl_xor(mk, off, 64);
            mk = (o > mk) ? o : mk;
        }
        const float mx = unmono32(mk);

        // compact kept (index order)
        int n = 0;
#pragma unroll
        for (int j = 0; j < 32; j++) {
            const bool p = (mv[j] >= lo);
            const unsigned long long ball = __ballot(p);
            if (p) {
                const int pos = n + (int)__popcll(ball & laneLT);
                if (pos < 64) {
                    kls[rr][pos] = lane + 64 * j;
                    wls[rr][pos] = expf(unmono32(mv[j]) - mx);
                }
            }
            n += (int)__popcll(ball);
        }
        if (n > 64) n = 64;

        float dl = (lane < n) ? wls[rr][lane] : 0.0f;
#pragma unroll
        for (int off = 32; off > 0; off >>= 1) dl += __shfl_xor(dl, off, 64);
        const float rden = 1.0f / dl;

        float acc = 0.0f;
        for (int c = 0; c < n; c++)
            acc = fmaf(wls[rr][c], Vb[(size_t)kls[rr][c] * HD + lane], acc);

        ctx[((size_t)b * LL + l0 + rr) * DM + h * HD + lane] = acc * rden;
    }
}

// ---------------------------------------------------------------------------
extern "C" void kernel_launch(void* const* d_in, const int* in_sizes, int n_in,
                              void* d_out, int out_size, void* d_ws, size_t ws_size,
                              hipStream_t stream)
{
    const float* x  = (const float*)d_in[0];
    const float* Wq = (const float*)d_in[1];
    const float* bq = (const float*)d_in[2];
    const float* Wk = (const float*)d_in[3];
    const float* bk = (const float*)d_in[4];
    const float* Wv = (const float*)d_in[5];
    const float* bv = (const float*)d_in[6];
    const float* Wo = (const float*)d_in[7];
    const float* bo = (const float*)d_in[8];
    float* out = (float*)d_out;

    const size_t E = (size_t)BB * NH * LL * HD;   // 4M elements
    float* Wt1 = (float*)d_ws;                    // 4 MB
    float* Wt2 = Wt1 + (size_t)DM * DM;           // 4 MB
    float* Qf  = Wt2 + (size_t)DM * DM;           // 16 MB
    float* Kf  = Qf + E;                          // 16 MB
    float* Vf  = Kf + E;                          // 16 MB
    float* ctx = Vf + E;                          // 16 MB   (72 MB total)
    unsigned* scw = (unsigned*)(ctx + E);         // scores chunks (<=128 MB)

    int U = (int)(5.0 * log((double)LL));
    if (U > LL) U = LL;

    // chunk size in (b,h) panels, bounded by remaining workspace
    const size_t base_bytes = (size_t)72 * 1024 * 1024;
    const size_t per_bh = (size_t)LL * LL * 4;    // 16 MB per panel
    size_t avail = (ws_size > base_bytes) ? (ws_size - base_bytes) : 0;
    int chunk = (int)(avail / per_bh);
    if (chunk < 1) chunk = 1;
    if (chunk > 8) chunk = 8;

    const int M = BB * LL;  // 4096
    dim3 blk(256);
    dim3 gT(DM / 32, DM / 32);
    dim3 gP(DM / 256, M / 8);
    dim3 g64(DM / 64, M / 64);

    hipLaunchKernelGGL(transpose1024, gT, blk, 0, stream, Wq, Wt1);
    hipLaunchKernelGGL(transpose1024, gT, blk, 0, stream, Wk, Wt2);
    hipLaunchKernelGGL(proj_emul, gP, blk, 0, stream, x, Wt1, bq, Qf);
    hipLaunchKernelGGL(proj_emul, gP, blk, 0, stream, x, Wt2, bk, Kf);
    hipLaunchKernelGGL((gemm_f32<0>), g64, blk, 0, stream, x, Wv, bv, Vf, M, DM, DM);

    for (int bh0 = 0; bh0 < BB * NH; bh0 += chunk) {
        int nb = BB * NH - bh0;
        if (nb > chunk) nb = chunk;
        dim3 gA(LL / 8, nb);
        hipLaunchKernelGGL(score_np,  gA, blk, 0, stream, Qf, Kf, scw, bh0);
        hipLaunchKernelGGL(select_np, gA, blk, 0, stream, scw, Vf, ctx, U, bh0);
    }

    hipLaunchKernelGGL((gemm_f32<1>), g64, blk, 0, stream, ctx, Wo, bo, out, M, DM, DM);
}

// Round 8
// 1680.944 us; speedup vs baseline: 3.6204x; 1.1588x over previous
//
#include <hip/hip_runtime.h>
#include <math.h>

#define BB 2
#define LL 2048
#define DM 1024
#define NH 16
#define HD 64

__device__ __forceinline__ unsigned mono32(float f) {
    unsigned u = __float_as_uint(f);
    return (u & 0x80000000u) ? ~u : (u | 0x80000000u);
}
__device__ __forceinline__ float unmono32(unsigned m) {
    const unsigned u = (m & 0x80000000u) ? (m & 0x7FFFFFFFu) : ~m;
    return __uint_as_float(u);
}

// ---------------------------------------------------------------------------
// 1024x1024 transpose: out[k][n] = in[n][k]
// ---------------------------------------------------------------------------
__global__ __launch_bounds__(256) void transpose1024(
    const float* __restrict__ in, float* __restrict__ out)
{
    __shared__ float t[32][33];
    const int bx = blockIdx.x * 32, by = blockIdx.y * 32;
    const int tx = threadIdx.x & 31, ty = threadIdx.x >> 5;
    for (int r = ty; r < 32; r += 8)
        t[r][tx] = in[(size_t)(by + r) * DM + bx + tx];
    __syncthreads();
    for (int r = ty; r < 32; r += 8)
        out[(size_t)(bx + r) * DM + by + tx] = t[tx][r];
}

// ---------------------------------------------------------------------------
// Bit-emulated f32 projection (numpy -> OpenBLAS sgemm, Zen/Haswell):
// K-panels (384,320,320); serial ascending-k FMA chain per panel; C += panel;
// then +bias. Scatter to [B,H,L,D]. Wt is W transposed [k][n].
// v2 (R8): 4 columns/thread (float4 W loads) + float4 LDS x reads. Per-output
// fmaf chain is IDENTICAL (k ascending per (m,n), panel C+= order kept) ->
// bit-exact. v1 was LDS-pipe bound: 8 scalar ds_read_b32 broadcasts per k
// vs only 8 FMAs (62% VALUBusy, 30.9 TF). Now 32 FMA / 2 ds_read_b128 per k.
// DO NOT TOUCH chain order: Q/K bit-exactness determines top-k selection.
// ---------------------------------------------------------------------------
__global__ __launch_bounds__(256) void proj_emul(
    const float* __restrict__ x, const float* __restrict__ Wt,
    const float* __restrict__ bias, float* __restrict__ outp)
{
    __shared__ float xs[8][DM];   // 32 KB
    const int tid = threadIdx.x;
    const int n4  = tid * 4;                 // 4 consecutive cols per thread
    const int m0  = blockIdx.x * 8;

    for (int i = tid; i < 8 * 256; i += 256) {
        const int r = i >> 8, c4 = (i & 255) << 2;
        *(float4*)&xs[r][c4] = *(const float4*)&x[(size_t)(m0 + r) * DM + c4];
    }
    __syncthreads();

    const int kbound[4] = {0, 384, 704, 1024};   // OpenBLAS Zen panel splits
                                                 // (all %4 == 0)
    float S[8][4] = {};
#pragma unroll
    for (int p = 0; p < 3; p++) {
        float P[8][4] = {};
        for (int k = kbound[p]; k < kbound[p + 1]; k += 4) {
            const float4 w0 = *(const float4*)&Wt[(size_t)(k + 0) * DM + n4];
            const float4 w1 = *(const float4*)&Wt[(size_t)(k + 1) * DM + n4];
            const float4 w2 = *(const float4*)&Wt[(size_t)(k + 2) * DM + n4];
            const float4 w3 = *(const float4*)&Wt[(size_t)(k + 3) * DM + n4];
#pragma unroll
            for (int m = 0; m < 8; m++) {
                const float4 xv = *(const float4*)&xs[m][k];
                // per (m,j) the k order is k,k+1,k+2,k+3 — ascending, exact
                P[m][0] = fmaf(xv.x, w0.x, P[m][0]);
                P[m][1] = fmaf(xv.x, w0.y, P[m][1]);
                P[m][2] = fmaf(xv.x, w0.z, P[m][2]);
                P[m][3] = fmaf(xv.x, w0.w, P[m][3]);
                P[m][0] = fmaf(xv.y, w1.x, P[m][0]);
                P[m][1] = fmaf(xv.y, w1.y, P[m][1]);
                P[m][2] = fmaf(xv.y, w1.z, P[m][2]);
                P[m][3] = fmaf(xv.y, w1.w, P[m][3]);
                P[m][0] = fmaf(xv.z, w2.x, P[m][0]);
                P[m][1] = fmaf(xv.z, w2.y, P[m][1]);
                P[m][2] = fmaf(xv.z, w2.z, P[m][2]);
                P[m][3] = fmaf(xv.z, w2.w, P[m][3]);
                P[m][0] = fmaf(xv.w, w3.x, P[m][0]);
                P[m][1] = fmaf(xv.w, w3.y, P[m][1]);
                P[m][2] = fmaf(xv.w, w3.z, P[m][2]);
                P[m][3] = fmaf(xv.w, w3.w, P[m][3]);
            }
        }
#pragma unroll
        for (int m = 0; m < 8; m++) {
#pragma unroll
            for (int j = 0; j < 4; j++) S[m][j] += P[m][j];  // C += panel
        }
    }

    const float4 b4v = *(const float4*)&bias[n4];
    const int h = n4 / HD, d0 = n4 % HD;   // 4 cols stay in one head
#pragma unroll
    for (int m = 0; m < 8; m++) {
        const int mm = m0 + m;
        const int b = mm / LL, l = mm % LL;
        float4 o;
        o.x = S[m][0] + b4v.x; o.y = S[m][1] + b4v.y;
        o.z = S[m][2] + b4v.z; o.w = S[m][3] + b4v.w;
        *(float4*)&outp[(((size_t)b * NH + h) * LL + l) * HD + d0] = o;
    }
}

// ---------------------------------------------------------------------------
// f32 GEMM for V (MODE 0 scatter) and output projection (MODE 1).
// ---------------------------------------------------------------------------
template <int MODE>
__global__ __launch_bounds__(256) void gemm_f32(
    const float* __restrict__ A, const float* __restrict__ W,
    const float* __restrict__ bias, float* __restrict__ out,
    int M, int N, int K)
{
    __shared__ float As[16][64];
    __shared__ float Bs[16][64];
    const int tid = threadIdx.x;
    const int m0 = blockIdx.y * 64;
    const int n0 = blockIdx.x * 64;
    const int tx = tid & 15, ty = tid >> 4;
    const int lr = tid >> 2, lc = (tid & 3) * 4;

    float acc[4][4] = {};

    for (int k0 = 0; k0 < K; k0 += 16) {
        float4 a4 = *(const float4*)&A[(size_t)(m0 + lr) * K + k0 + lc];
        float4 b4 = *(const float4*)&W[(size_t)(n0 + lr) * K + k0 + lc];
        __syncthreads();
        As[lc + 0][lr] = a4.x; As[lc + 1][lr] = a4.y;
        As[lc + 2][lr] = a4.z; As[lc + 3][lr] = a4.w;
        Bs[lc + 0][lr] = b4.x; Bs[lc + 1][lr] = b4.y;
        Bs[lc + 2][lr] = b4.z; Bs[lc + 3][lr] = b4.w;
        __syncthreads();
#pragma unroll
        for (int kk = 0; kk < 16; kk++) {
            float4 av = *(const float4*)&As[kk][ty * 4];
            float4 bv = *(const float4*)&Bs[kk][tx * 4];
            float a[4] = {av.x, av.y, av.z, av.w};
            float b[4] = {bv.x, bv.y, bv.z, bv.w};
#pragma unroll
            for (int i = 0; i < 4; i++)
#pragma unroll
                for (int j = 0; j < 4; j++)
                    acc[i][j] = fmaf(a[i], b[j], acc[i][j]);
        }
    }

#pragma unroll
    for (int i = 0; i < 4; i++) {
        const int m = m0 + ty * 4 + i;
#pragma unroll
        for (int j = 0; j < 4; j++) {
            const int n = n0 + tx * 4 + j;
            const float v = acc[i][j] + bias[n];
            if (MODE == 0) {
                const int b = m / LL, l = m % LL;
                const int h = n / HD, d = n % HD;
                out[(((size_t)b * NH + h) * LL + l) * HD + d] = v;
            } else {
                out[(size_t)m * N + n] = v;
            }
        }
    }
}

// ---------------------------------------------------------------------------
// Attention: score_np (producer) + select_np (consumer), split in R7 to kill
// the structural 64-reg live range that spilled in v3-v6 (regalloc, not SROA).
//
// score_np v2 (R8): 4 q-rows per wave (16 per block) — K-tile LDS reads and
// staging amortize over 2x rows. Per-row chain ops/order IDENTICAL
// (mul+add, contract off) -> bit-exact. Scores stored immediately to global
// as monotone u32 (coalesced), no per-thread arrays.
// select_np: R0-proven consumer; mv[32] short live range -> registers.
// ---------------------------------------------------------------------------
__global__ __launch_bounds__(256) void score_np(
    const float* __restrict__ Qf, const float* __restrict__ Kf,
    unsigned* __restrict__ scw, int bh0)
{
#pragma clang fp contract(off)
    const int tid  = threadIdx.x;
    const int lane = tid & 63;
    const int wv   = tid >> 6;
    const int l0   = blockIdx.x * 16;
    const int bhl  = blockIdx.y;
    const int bh   = bh0 + bhl;

    __shared__ float kt[2][64][68];    // 34 KB K tiles (+4 pad per row)
    __shared__ float qsh[16][64];      // 4 KB

    const float* __restrict__ Kb = Kf + (size_t)bh * LL * HD;

    // stage q rows: 256 threads = 16 rows x 16 float4, one each
    {
        const int r = tid >> 4, d4q = tid & 15;
        *(float4*)&qsh[r][d4q * 4] =
            *(const float4*)&Qf[((size_t)bh * LL + l0 + r) * HD + d4q * 4];
    }
    // stage K tile 0 (64 rows x 16 float4; coalesced)
#pragma unroll
    for (int i = 0; i < 4; i++) {
        const int idx = i * 256 + tid;
        *(float4*)&kt[0][idx >> 4][(idx & 15) * 4] =
            *(const float4*)&Kb[(size_t)(idx >> 4) * HD + (idx & 15) * 4];
    }
    __syncthreads();

    const int r0 = wv * 4;
    unsigned* __restrict__ s0 = scw + ((size_t)bhl * LL + l0 + r0 + 0) * LL;
    unsigned* __restrict__ s1 = scw + ((size_t)bhl * LL + l0 + r0 + 1) * LL;
    unsigned* __restrict__ s2 = scw + ((size_t)bhl * LL + l0 + r0 + 2) * LL;
    unsigned* __restrict__ s3 = scw + ((size_t)bhl * LL + l0 + r0 + 3) * LL;

    for (int tile = 0; tile < 32; tile++) {
        const int buf = tile & 1;
        float4 pf0, pf1, pf2, pf3;
        if (tile < 31) {
            const float* src = Kb + (size_t)(tile + 1) * 64 * HD;
            pf0 = *(const float4*)&src[(size_t)((0 * 256 + tid) >> 4) * HD + ((0 * 256 + tid) & 15) * 4];
            pf1 = *(const float4*)&src[(size_t)((1 * 256 + tid) >> 4) * HD + ((1 * 256 + tid) & 15) * 4];
            pf2 = *(const float4*)&src[(size_t)((2 * 256 + tid) >> 4) * HD + ((2 * 256 + tid) & 15) * 4];
            pf3 = *(const float4*)&src[(size_t)((3 * 256 + tid) >> 4) * HD + ((3 * 256 + tid) & 15) * 4];
        }

        // scores for key = tile*64 + lane, rows r0..r0+3 (bit-exact chains,
        // independent per row; per-row op order identical to v1)
        float ax0 = 0, ay0 = 0, az0 = 0, aw0 = 0;
        float ax1 = 0, ay1 = 0, az1 = 0, aw1 = 0;
        float ax2 = 0, ay2 = 0, az2 = 0, aw2 = 0;
        float ax3 = 0, ay3 = 0, az3 = 0, aw3 = 0;
        const float* krow = &kt[buf][lane][0];
        const float* q0 = &qsh[r0 + 0][0];
        const float* q1 = &qsh[r0 + 1][0];
        const float* q2 = &qsh[r0 + 2][0];
        const float* q3 = &qsh[r0 + 3][0];
#pragma unroll
        for (int t = 0; t < 4; t++) {
#pragma unroll
            for (int sub = 3; sub >= 0; sub--) {
                const int d4 = 4 * t + sub;
                const float4 kf = *(const float4*)&krow[d4 * 4];
                const float4 qa = *(const float4*)&q0[d4 * 4];
                const float4 qb = *(const float4*)&q1[d4 * 4];
                const float4 qc = *(const float4*)&q2[d4 * 4];
                const float4 qd = *(const float4*)&q3[d4 * 4];
                ax0 = qa.x * kf.x + ax0; ay0 = qa.y * kf.y + ay0;
                az0 = qa.z * kf.z + az0; aw0 = qa.w * kf.w + aw0;
                ax1 = qb.x * kf.x + ax1; ay1 = qb.y * kf.y + ay1;
                az1 = qb.z * kf.z + az1; aw1 = qb.w * kf.w + aw1;
                ax2 = qc.x * kf.x + ax2; ay2 = qc.y * kf.y + ay2;
                az2 = qc.z * kf.z + az2; aw2 = qc.w * kf.w + aw2;
                ax3 = qd.x * kf.x + ax3; ay3 = qd.y * kf.y + ay3;
                az3 = qd.z * kf.z + az3; aw3 = qd.w * kf.w + aw3;
            }
        }
        // immediate coalesced stores (lane-consecutive u32), no live range
        s0[tile * 64 + lane] = mono32(((ax0 + ay0) + (az0 + aw0)) * 0.125f);
        s1[tile * 64 + lane] = mono32(((ax1 + ay1) + (az1 + aw1)) * 0.125f);
        s2[tile * 64 + lane] = mono32(((ax2 + ay2) + (az2 + aw2)) * 0.125f);
        s3[tile * 64 + lane] = mono32(((ax3 + ay3) + (az3 + aw3)) * 0.125f);

        if (tile < 31) {
            // single barrier per tile: reads kt[buf] / writes kt[buf^1]
            // are disjoint buffers.
            *(float4*)&kt[buf ^ 1][(0 * 256 + tid) >> 4][((0 * 256 + tid) & 15) * 4] = pf0;
            *(float4*)&kt[buf ^ 1][(1 * 256 + tid) >> 4][((1 * 256 + tid) & 15) * 4] = pf1;
            *(float4*)&kt[buf ^ 1][(2 * 256 + tid) >> 4][((2 * 256 + tid) & 15) * 4] = pf2;
            *(float4*)&kt[buf ^ 1][(3 * 256 + tid) >> 4][((3 * 256 + tid) & 15) * 4] = pf3;
            __syncthreads();
        }
    }
}

__global__ __launch_bounds__(256) void select_np(
    const unsigned* __restrict__ scw, const float* __restrict__ Vf,
    float* __restrict__ ctx, int U, int bh0)
{
#pragma clang fp contract(off)
    const int tid  = threadIdx.x;
    const int lane = tid & 63;
    const int wv   = tid >> 6;
    const int l0   = blockIdx.x * 8;
    const int bhl  = blockIdx.y;
    const int bh   = bh0 + bhl;
    const int b    = bh / NH;
    const int h    = bh % NH;

    __shared__ float wls[8][64];       // 2 KB
    __shared__ int   kls[8][64];       // 2 KB

    const unsigned long long laneLT = (1ull << lane) - 1ull;
    const float* __restrict__ Vb = Vf + (size_t)bh * LL * HD;

#pragma unroll
    for (int rr8 = 0; rr8 < 2; rr8++) {
        const int rr = wv * 2 + rr8;
        const unsigned* __restrict__ srow =
            scw + ((size_t)bhl * LL + l0 + rr) * LL;

        // own-lane scores, coalesced load; SHORT live range -> registers
        unsigned mv[32];
#pragma unroll
        for (int j = 0; j < 32; j++) mv[j] = srow[lane + 64 * j];

        // exact U-th-largest key (largest T with count(>=T) >= U)
        unsigned lo = 0u, hi = 0xFFFFFFFFu;
        while (lo < hi) {
            const unsigned span = hi - lo;
            const unsigned mid = lo + (span >> 1) + (span & 1u);
            int c = 0;
#pragma unroll
            for (int j = 0; j < 32; j++)
                c += (int)__popcll(__ballot(mv[j] >= mid));
            if (c >= U) lo = mid; else hi = mid - 1u;
        }

        // max kept (reduce in key domain; lanes w/o kept contribute 0)
        unsigned mk = 0;
#pragma unroll
        for (int j = 0; j < 32; j++)
            if (mv[j] >= lo) mk = (mv[j] > mk) ? mv[j] : mk;
#pragma unroll
        for (int off = 32; off > 0; off >>= 1) {
            const unsigned o = __shfl_xor(mk, off, 64);
            mk = (o > mk) ? o : mk;
        }
        const float mx = unmono32(mk);

        // compact kept (index order)
        int n = 0;
#pragma unroll
        for (int j = 0; j < 32; j++) {
            const bool p = (mv[j] >= lo);
            const unsigned long long ball = __ballot(p);
            if (p) {
                const int pos = n + (int)__popcll(ball & laneLT);
                if (pos < 64) {
                    kls[rr][pos] = lane + 64 * j;
                    wls[rr][pos] = expf(unmono32(mv[j]) - mx);
                }
            }
            n += (int)__popcll(ball);
        }
        if (n > 64) n = 64;

        float dl = (lane < n) ? wls[rr][lane] : 0.0f;
#pragma unroll
        for (int off = 32; off > 0; off >>= 1) dl += __shfl_xor(dl, off, 64);
        const float rden = 1.0f / dl;

        float acc = 0.0f;
        for (int c = 0; c < n; c++)
            acc = fmaf(wls[rr][c], Vb[(size_t)kls[rr][c] * HD + lane], acc);

        ctx[((size_t)b * LL + l0 + rr) * DM + h * HD + lane] = acc * rden;
    }
}

// ---------------------------------------------------------------------------
extern "C" void kernel_launch(void* const* d_in, const int* in_sizes, int n_in,
                              void* d_out, int out_size, void* d_ws, size_t ws_size,
                              hipStream_t stream)
{
    const float* x  = (const float*)d_in[0];
    const float* Wq = (const float*)d_in[1];
    const float* bq = (const float*)d_in[2];
    const float* Wk = (const float*)d_in[3];
    const float* bk = (const float*)d_in[4];
    const float* Wv = (const float*)d_in[5];
    const float* bv = (const float*)d_in[6];
    const float* Wo = (const float*)d_in[7];
    const float* bo = (const float*)d_in[8];
    float* out = (float*)d_out;

    const size_t E = (size_t)BB * NH * LL * HD;   // 4M elements
    float* Wt1 = (float*)d_ws;                    // 4 MB
    float* Wt2 = Wt1 + (size_t)DM * DM;           // 4 MB
    float* Qf  = Wt2 + (size_t)DM * DM;           // 16 MB
    float* Kf  = Qf + E;                          // 16 MB
    float* Vf  = Kf + E;                          // 16 MB
    float* ctx = Vf + E;                          // 16 MB   (72 MB total)
    unsigned* scw = (unsigned*)(ctx + E);         // scores chunks (<=128 MB)

    int U = (int)(5.0 * log((double)LL));
    if (U > LL) U = LL;

    // chunk size in (b,h) panels, bounded by remaining workspace
    const size_t base_bytes = (size_t)72 * 1024 * 1024;
    const size_t per_bh = (size_t)LL * LL * 4;    // 16 MB per panel
    size_t avail = (ws_size > base_bytes) ? (ws_size - base_bytes) : 0;
    int chunk = (int)(avail / per_bh);
    if (chunk < 1) chunk = 1;
    if (chunk > 8) chunk = 8;

    const int M = BB * LL;  // 4096
    dim3 blk(256);
    dim3 gT(DM / 32, DM / 32);
    dim3 gP(M / 8);
    dim3 g64(DM / 64, M / 64);

    hipLaunchKernelGGL(transpose1024, gT, blk, 0, stream, Wq, Wt1);
    hipLaunchKernelGGL(transpose1024, gT, blk, 0, stream, Wk, Wt2);
    hipLaunchKernelGGL(proj_emul, gP, blk, 0, stream, x, Wt1, bq, Qf);
    hipLaunchKernelGGL(proj_emul, gP, blk, 0, stream, x, Wt2, bk, Kf);
    hipLaunchKernelGGL((gemm_f32<0>), g64, blk, 0, stream, x, Wv, bv, Vf, M, DM, DM);

    for (int bh0 = 0; bh0 < BB * NH; bh0 += chunk) {
        int nb = BB * NH - bh0;
        if (nb > chunk) nb = chunk;
        dim3 gA(LL / 16, nb);
        dim3 gS(LL / 8, nb);
        hipLaunchKernelGGL(score_np,  gA, blk, 0, stream, Qf, Kf, scw, bh0);
        hipLaunchKernelGGL(select_np, gS, blk, 0, stream, scw, Vf, ctx, U, bh0);
    }

    hipLaunchKernelGGL((gemm_f32<1>), g64, blk, 0, stream, ctx, Wo, bo, out, M, DM, DM);
}